// Round 2
// 570.772 us; speedup vs baseline: 1.1623x; 1.1623x over previous
//
#include <hip/hip_runtime.h>
#include <stdint.h>

constexpr int B = 8, N = 1024, C = 768, H = 12, D = 64;
constexpr int M = B * N;          // 8192
constexpr int NQKV = 3 * C;       // 2304
constexpr float SCALE = 0.125f;   // 1/sqrt(64)

typedef _Float16 f16;
typedef _Float16 f16x8 __attribute__((ext_vector_type(8)));
typedef _Float16 f16x4 __attribute__((ext_vector_type(4)));
typedef float    f32x4 __attribute__((ext_vector_type(4)));

// compiler memory fence (no code) — raw s_barrier is IntrNoMem, so every
// barrier must be bracketed to stop IR-level load/store motion across it.
#define FENCE() asm volatile("" ::: "memory")
#define BARRIER() do { FENCE(); __builtin_amdgcn_s_barrier(); FENCE(); } while (0)
#define WAIT_LGKM0() asm volatile("s_waitcnt lgkmcnt(0)" ::: "memory")

// global->LDS 16B DMA. LDS side: wave-uniform base, HW adds lane*16.
__device__ __forceinline__ void gl_lds16(const void* g, void* lds_base) {
    auto gp = (const __attribute__((address_space(1))) uint32_t*)(uintptr_t)g;
    auto lp = (__attribute__((address_space(3))) uint32_t*)(uint32_t)(uintptr_t)lds_base;
    __builtin_amdgcn_global_load_lds(gp, lp, 16, 0, 0);
}

// ---------------------------------------------------------------------------
// x (fp32) -> xh (fp16), elementwise
// ---------------------------------------------------------------------------
__global__ __launch_bounds__(256)
void conv_x_kernel(const float* __restrict__ x, f16* __restrict__ xh)
{
    size_t i = (size_t)blockIdx.x * 256 + threadIdx.x;
    float4 v = ((const float4*)x)[i];
    f16x4 h = { (f16)v.x, (f16)v.y, (f16)v.z, (f16)v.w };
    *(f16x4*)(xh + 4 * i) = h;
}

// ---------------------------------------------------------------------------
// src[rows][cols] fp32 -> dst[cols][rows] fp16  (32x32 LDS tile transpose)
// ---------------------------------------------------------------------------
__global__ __launch_bounds__(256)
void transpose_conv(const float* __restrict__ src, f16* __restrict__ dst,
                    int rows, int cols)
{
    __shared__ float tile[32][33];
    const int tx = threadIdx.x & 31, ty = threadIdx.x >> 5;
    const int bx = blockIdx.x * 32, by = blockIdx.y * 32;
    #pragma unroll
    for (int i = 0; i < 4; ++i)
        tile[ty + 8 * i][tx] = src[(size_t)(by + ty + 8 * i) * cols + bx + tx];
    __syncthreads();
    #pragma unroll
    for (int i = 0; i < 4; ++i)
        dst[(size_t)(bx + ty + 8 * i) * rows + by + tx] = (f16)tile[tx][ty + 8 * i];
}

// ---------------------------------------------------------------------------
// qkv GEMM: A[8192][768] fp16 @ Bt[2304][768]^T, 128x128 tile, BK=32, MFMA.
// Epilogue scatters to q,k [B,H,N,D] fp16 and v^T [B,H,D,N] fp16.
// ---------------------------------------------------------------------------
__global__ __launch_bounds__(256)
void qkv_gemm_h(const f16* __restrict__ A, const f16* __restrict__ Bt,
                f16* __restrict__ qh, f16* __restrict__ kh, f16* __restrict__ vth)
{
    __shared__ f16 Ah[128 * 32];
    __shared__ f16 Bh[128 * 32];
    const int t = threadIdx.x, w = t >> 6, l = t & 63;
    const int mbase = blockIdx.y * 128, nbase = blockIdx.x * 128;
    const int wm = (w >> 1) * 64, wn = (w & 1) * 64;
    const int fr = l & 15, fq = l >> 4;

    f32x4 acc[4][4];
    #pragma unroll
    for (int i = 0; i < 4; ++i)
        #pragma unroll
        for (int j = 0; j < 4; ++j) acc[i][j] = (f32x4){0.f, 0.f, 0.f, 0.f};

    for (int kb = 0; kb < 768; kb += 32) {
        #pragma unroll
        for (int i = 0; i < 2; ++i) {
            int p = w * 2 + i;
            int r = p * 16 + (l >> 2), c = l & 3;
            gl_lds16(A + (size_t)(mbase + r) * 768 + kb + c * 8, Ah + p * 512);
            gl_lds16(Bt + (size_t)(nbase + r) * 768 + kb + c * 8, Bh + p * 512);
        }
        __syncthreads();
        f16x8 af[4], bf[4];
        #pragma unroll
        for (int mt = 0; mt < 4; ++mt)
            af[mt] = *(const f16x8*)&Ah[(wm + mt * 16 + fr) * 32 + fq * 8];
        #pragma unroll
        for (int nt = 0; nt < 4; ++nt)
            bf[nt] = *(const f16x8*)&Bh[(wn + nt * 16 + fr) * 32 + fq * 8];
        #pragma unroll
        for (int mt = 0; mt < 4; ++mt)
            #pragma unroll
            for (int nt = 0; nt < 4; ++nt)
                acc[mt][nt] = __builtin_amdgcn_mfma_f32_16x16x32_f16(af[mt], bf[nt], acc[mt][nt], 0, 0, 0);
        __syncthreads();
    }

    const int seg = nbase / 768;      // 0=q 1=k 2=v, uniform per block
    #pragma unroll
    for (int mt = 0; mt < 4; ++mt) {
        int tok0 = mbase + wm + mt * 16 + fq * 4;
        int bb = tok0 >> 10, nn0 = tok0 & 1023;
        #pragma unroll
        for (int nt = 0; nt < 4; ++nt) {
            int od = nbase + wn + nt * 16 + fr;
            int rem = od - seg * 768;
            int hh = rem >> 6, dd = rem & 63;
            if (seg == 2) {
                f16x4 pv = { (f16)acc[mt][nt][0], (f16)acc[mt][nt][1],
                             (f16)acc[mt][nt][2], (f16)acc[mt][nt][3] };
                *(f16x4*)(vth + ((size_t)(bb * H + hh) * 64 + dd) * 1024 + nn0) = pv;
            } else {
                f16* dst = (seg == 0) ? qh : kh;
                size_t base = (size_t)(bb * H + hh) * 1024;
                #pragma unroll
                for (int rg = 0; rg < 4; ++rg)
                    dst[(base + nn0 + rg) * 64 + dd] = (f16)acc[mt][nt][rg];
            }
        }
    }
}

// ---------------------------------------------------------------------------
// Fused attention: one block per (b,h, 32 Q rows), 512 threads / 8 waves.
// Wave (rg,cg): rg=w>>2 owns rows rg*16.., cg=w&3 owns col/dim slice.
// S kept fp32 in regs (64/lane). K/V chunks double-buffered in LDS with
// counted vmcnt(2) prefetch. All barriers fenced; every compute phase drains
// lgkmcnt BEFORE its closing barrier (reads complete before buffer reuse).
// ---------------------------------------------------------------------------
__global__ __launch_bounds__(512, 4)
void attn_fused(const f16* __restrict__ qh, const f16* __restrict__ kh,
                const f16* __restrict__ vth, float* __restrict__ attn,
                f16* __restrict__ ctxh)
{
    __shared__ f16 sQ[32 * 72];          // 4.5 KB
    __shared__ f16 sKV[2][8192];         // 2 x 16 KB (K chunks, then V^T chunks)
    __shared__ f16 sP2[2][32 * 136];     // 2 x 8.5 KB per-chunk P (fp16)
    __shared__ float sRed[2][8][32];     // 2 KB cross-wave softmax reduce

    const int t = threadIdx.x, w = t >> 6, l = t & 63;
    const int rg = w >> 2, cg = w & 3;
    const int bh = blockIdx.x >> 5, qt = blockIdx.x & 31;
    const int row0 = qt * 32;
    const size_t kvbase = (size_t)bh * (1024 * 64);
    const int fr = l & 15, fq = l >> 4;

    auto stageK = [&](int jc, f16* dst) {
        #pragma unroll
        for (int i = 0; i < 2; ++i) {
            int p = w * 2 + i;                       // 0..15, 8 rows each
            int r = p * 8 + (l >> 3);                // key row 0..127
            int c = (l & 7) ^ (r & 7);               // xor-swizzled 16B slot
            gl_lds16(kh + kvbase + (size_t)(jc * 128 + r) * 64 + c * 8, dst + p * 512);
        }
    };
    auto stageV = [&](int jc, f16* dst) {
        #pragma unroll
        for (int i = 0; i < 2; ++i) {
            int p = w * 2 + i;                       // 0..15, 4 d-rows each
            int r = p * 4 + (l >> 4);                // d row 0..63
            int c = (l & 15) ^ (r & 15);             // swizzled 16B slot (16/row)
            gl_lds16(vth + kvbase + (size_t)r * 1024 + jc * 128 + c * 8, dst + p * 512);
        }
    };

    // ---- stage Q tile 32x64 (reg->LDS), prefetch K chunk 0 under it ----
    {
        int r = t >> 4, d4 = (t & 15) * 4;
        f16x4 qv = *(const f16x4*)(qh + kvbase + (size_t)(row0 + r) * 64 + d4);
        stageK(0, sKV[0]);
        *(f16x4*)&sQ[r * 72 + d4] = qv;
    }
    WAIT_LGKM0();
    BARRIER();

    f16x8 af[2];
    #pragma unroll
    for (int ks = 0; ks < 2; ++ks)
        af[ks] = *(const f16x8*)&sQ[(rg * 16 + fr) * 72 + ks * 32 + fq * 8];

    f32x4 sacc[8][2];
    #pragma unroll
    for (int jc = 0; jc < 8; ++jc) {
        sacc[jc][0] = (f32x4){0.f, 0.f, 0.f, 0.f};
        sacc[jc][1] = (f32x4){0.f, 0.f, 0.f, 0.f};
    }

    // ---- S = Q K^T : 8 chunks of 128 keys, double-buffered, counted vmcnt ----
    #pragma unroll
    for (int jc = 0; jc < 8; ++jc) {
        const int cur = jc & 1;
        if (jc < 7) {
            stageK(jc + 1, sKV[cur ^ 1]);
            asm volatile("s_waitcnt vmcnt(2)" ::: "memory");   // chunk jc landed
        } else {
            asm volatile("s_waitcnt vmcnt(0)" ::: "memory");
        }
        BARRIER();
        __builtin_amdgcn_sched_barrier(0);
        #pragma unroll
        for (int nt2 = 0; nt2 < 2; ++nt2) {
            int brow = cg * 32 + nt2 * 16 + fr;
            #pragma unroll
            for (int ks = 0; ks < 2; ++ks) {
                int slot = (ks * 4 + fq) ^ (brow & 7);
                f16x8 bf = *(const f16x8*)&sKV[cur][brow * 64 + slot * 8];
                sacc[jc][nt2] = __builtin_amdgcn_mfma_f32_16x16x32_f16(af[ks], bf, sacc[jc][nt2], 0, 0, 0);
            }
        }
        WAIT_LGKM0();          // my LDS reads complete before anyone reuses buffer
        BARRIER();
    }

    // prefetch V chunk 0 now — latency hides under softmax (barriers below do
    // not drain vmcnt)
    stageV(0, sKV[0]);

    // ---- softmax over full 1024-wide rows (lane owns rows rg*16+fq*4+r) ----
    float mrow[4] = {-1e30f, -1e30f, -1e30f, -1e30f};
    #pragma unroll
    for (int jc = 0; jc < 8; ++jc)
        #pragma unroll
        for (int nt2 = 0; nt2 < 2; ++nt2)
            #pragma unroll
            for (int r = 0; r < 4; ++r)
                mrow[r] = fmaxf(mrow[r], sacc[jc][nt2][r]);
    #pragma unroll
    for (int off = 1; off < 16; off <<= 1)
        #pragma unroll
        for (int r = 0; r < 4; ++r)
            mrow[r] = fmaxf(mrow[r], __shfl_xor(mrow[r], off));
    if (fr == 0)
        #pragma unroll
        for (int r = 0; r < 4; ++r) sRed[0][w][rg * 16 + fq * 4 + r] = mrow[r];
    WAIT_LGKM0();
    BARRIER();

    float Mv[4];
    #pragma unroll
    for (int r = 0; r < 4; ++r) {
        int row = rg * 16 + fq * 4 + r;
        float m = fmaxf(fmaxf(sRed[0][rg * 4 + 0][row], sRed[0][rg * 4 + 1][row]),
                        fmaxf(sRed[0][rg * 4 + 2][row], sRed[0][rg * 4 + 3][row]));
        Mv[r] = m * SCALE;
    }
    float srow[4] = {0.f, 0.f, 0.f, 0.f};
    #pragma unroll
    for (int jc = 0; jc < 8; ++jc)
        #pragma unroll
        for (int nt2 = 0; nt2 < 2; ++nt2)
            #pragma unroll
            for (int r = 0; r < 4; ++r) {
                float p = __expf(sacc[jc][nt2][r] * SCALE - Mv[r]);
                sacc[jc][nt2][r] = p;
                srow[r] += p;
            }
    #pragma unroll
    for (int off = 1; off < 16; off <<= 1)
        #pragma unroll
        for (int r = 0; r < 4; ++r)
            srow[r] += __shfl_xor(srow[r], off);
    if (fr == 0)
        #pragma unroll
        for (int r = 0; r < 4; ++r) sRed[1][w][rg * 16 + fq * 4 + r] = srow[r];
    WAIT_LGKM0();
    BARRIER();

    float inv[4];
    #pragma unroll
    for (int r = 0; r < 4; ++r) {
        int row = rg * 16 + fq * 4 + r;
        inv[r] = 1.0f / (sRed[1][rg * 4 + 0][row] + sRed[1][rg * 4 + 1][row] +
                         sRed[1][rg * 4 + 2][row] + sRed[1][rg * 4 + 3][row]);
    }

    // ---- O = P V : 8 chunks, double-buffered V + per-chunk P tile in LDS ----
    f32x4 oacc = (f32x4){0.f, 0.f, 0.f, 0.f};
    #pragma unroll
    for (int jc = 0; jc < 8; ++jc) {
        const int cur = jc & 1;
        if (jc < 7) stageV(jc + 1, sKV[cur ^ 1]);
        // write normalized P chunk jc (fp16) into sP2[cur]
        #pragma unroll
        for (int nt2 = 0; nt2 < 2; ++nt2) {
            int col = cg * 32 + nt2 * 16 + fr;
            #pragma unroll
            for (int r = 0; r < 4; ++r) {
                int row = rg * 16 + fq * 4 + r;
                sP2[cur][row * 136 + col] = (f16)(sacc[jc][nt2][r] * inv[r]);
            }
        }
        if (jc < 7) asm volatile("s_waitcnt vmcnt(2) lgkmcnt(0)" ::: "memory");
        else        asm volatile("s_waitcnt vmcnt(0) lgkmcnt(0)" ::: "memory");
        BARRIER();
        __builtin_amdgcn_sched_barrier(0);
        #pragma unroll
        for (int ks = 0; ks < 4; ++ks) {
            f16x8 pf = *(const f16x8*)&sP2[cur][(rg * 16 + fr) * 136 + ks * 32 + fq * 8];
            int brow = cg * 16 + fr;
            int slot = (ks * 4 + fq) ^ (brow & 15);
            f16x8 vf = *(const f16x8*)&sKV[cur][brow * 128 + slot * 8];
            oacc = __builtin_amdgcn_mfma_f32_16x16x32_f16(pf, vf, oacc, 0, 0, 0);
        }
        WAIT_LGKM0();
        BARRIER();
    }

    // ---- write attn (fp32) from regs (after PV so stores don't pollute vmcnt) ----
    float* ab = attn + ((size_t)bh << 20) + (size_t)row0 * 1024;
    #pragma unroll
    for (int jc = 0; jc < 8; ++jc)
        #pragma unroll
        for (int nt2 = 0; nt2 < 2; ++nt2) {
            int col = jc * 128 + cg * 32 + nt2 * 16 + fr;
            #pragma unroll
            for (int r = 0; r < 4; ++r) {
                int row = rg * 16 + fq * 4 + r;
                ab[(size_t)row * 1024 + col] = sacc[jc][nt2][r] * inv[r];
            }
        }

    // ---- ctx write ----
    const int bb = bh / H, hh = bh - bb * H;
    int tok0 = bb * 1024 + row0 + rg * 16 + fq * 4;
    int cd = hh * 64 + cg * 16 + fr;
    #pragma unroll
    for (int rgi = 0; rgi < 4; ++rgi)
        ctxh[(size_t)(tok0 + rgi) * 768 + cd] = (f16)oacc[rgi];
}

// ---------------------------------------------------------------------------
// out = ctx @ w_proj + b_proj  (fp16 MFMA, fp32 out)
// ---------------------------------------------------------------------------
__global__ __launch_bounds__(256)
void proj_gemm_h(const f16* __restrict__ A, const f16* __restrict__ Bt,
                 const float* __restrict__ bias, float* __restrict__ out)
{
    __shared__ f16 Ah[128 * 32];
    __shared__ f16 Bh[128 * 32];
    const int t = threadIdx.x, w = t >> 6, l = t & 63;
    const int mbase = blockIdx.y * 128, nbase = blockIdx.x * 128;
    const int wm = (w >> 1) * 64, wn = (w & 1) * 64;
    const int fr = l & 15, fq = l >> 4;

    f32x4 acc[4][4];
    #pragma unroll
    for (int i = 0; i < 4; ++i)
        #pragma unroll
        for (int j = 0; j < 4; ++j) acc[i][j] = (f32x4){0.f, 0.f, 0.f, 0.f};

    for (int kb = 0; kb < 768; kb += 32) {
        #pragma unroll
        for (int i = 0; i < 2; ++i) {
            int p = w * 2 + i;
            int r = p * 16 + (l >> 2), c = l & 3;
            gl_lds16(A + (size_t)(mbase + r) * 768 + kb + c * 8, Ah + p * 512);
            gl_lds16(Bt + (size_t)(nbase + r) * 768 + kb + c * 8, Bh + p * 512);
        }
        __syncthreads();
        f16x8 af[4], bf[4];
        #pragma unroll
        for (int mt = 0; mt < 4; ++mt)
            af[mt] = *(const f16x8*)&Ah[(wm + mt * 16 + fr) * 32 + fq * 8];
        #pragma unroll
        for (int nt = 0; nt < 4; ++nt)
            bf[nt] = *(const f16x8*)&Bh[(wn + nt * 16 + fr) * 32 + fq * 8];
        #pragma unroll
        for (int mt = 0; mt < 4; ++mt)
            #pragma unroll
            for (int nt = 0; nt < 4; ++nt)
                acc[mt][nt] = __builtin_amdgcn_mfma_f32_16x16x32_f16(af[mt], bf[nt], acc[mt][nt], 0, 0, 0);
        __syncthreads();
    }

    #pragma unroll
    for (int mt = 0; mt < 4; ++mt) {
        int tok0 = mbase + wm + mt * 16 + fq * 4;
        #pragma unroll
        for (int nt = 0; nt < 4; ++nt) {
            int od = nbase + wn + nt * 16 + fr;
            float bv = bias[od];
            #pragma unroll
            for (int rg = 0; rg < 4; ++rg)
                out[(size_t)(tok0 + rg) * 768 + od] = acc[mt][nt][rg] + bv;
        }
    }
}

extern "C" void kernel_launch(void* const* d_in, const int* in_sizes, int n_in,
                              void* d_out, int out_size, void* d_ws, size_t ws_size,
                              hipStream_t stream)
{
    (void)in_sizes; (void)n_in; (void)out_size; (void)ws_size;
    const float* x      = (const float*)d_in[0];
    const float* w_qkv  = (const float*)d_in[1];
    const float* w_proj = (const float*)d_in[2];
    const float* b_proj = (const float*)d_in[3];

    float* out  = (float*)d_out;
    float* attn = out + (size_t)B * N * C;

    const size_t HND = (size_t)B * H * N * D;   // 6291456
    f16* xh     = (f16*)d_ws;
    f16* wqkvT  = xh + HND;                     // 2304*768 = 1769472
    f16* wprojT = wqkvT + 1769472;              // 768*768  = 589824
    f16* qh     = wprojT + 589824;
    f16* kh     = qh + HND;
    f16* vth    = kh + HND;
    f16* ctxh   = vth + HND;

    conv_x_kernel<<<dim3(6144), 256, 0, stream>>>(x, xh);
    transpose_conv<<<dim3(NQKV / 32, C / 32), 256, 0, stream>>>(w_qkv, wqkvT, C, NQKV);
    transpose_conv<<<dim3(C / 32, C / 32), 256, 0, stream>>>(w_proj, wprojT, C, C);
    qkv_gemm_h<<<dim3(NQKV / 128, M / 128), 256, 0, stream>>>(xh, wqkvT, qh, kh, vth);
    attn_fused<<<dim3(B * H * (N / 32)), 512, 0, stream>>>(qh, kh, vth, attn, ctxh);
    proj_gemm_h<<<dim3(C / 128, M / 128), 256, 0, stream>>>(ctxh, wprojT, b_proj, out);
}